// Round 3
// baseline (818.956 us; speedup 1.0000x reference)
//
#include <hip/hip_runtime.h>

// ---------------------------------------------------------------------------
// AveragedKeyCircularConvolutionalAttention  (B=2, N=2048, C=768, h=12, d=64)
// Single-dispatch mega-kernel: 512 blocks x 256 threads, all co-resident
// (launch_bounds(256,2) => 2 blocks/CU * 256 CUs = 512).
//
// Grid barrier v2 (R2's failed: shared cnt/gen line + relaxed spin):
//   - each block release-stores arrive[bid] (512 distinct lines, no RMW contention)
//   - master block's 256 threads ACQUIRE-poll all flags (per-poll buffer_inv
//     => always fresh), then release-stores gen
//   - everyone ACQUIRE-polls gen with s_sleep pacing
//
//  P0: x,Wv,Wp -> bf16  +  x column sums                         (512/96 blk)
//  P1: Ub = SCALE/2048 * (x_avg@Wk^T) @ Wq rows                  (24 blk)
//  P2: VT = (x@Wv^T)^T (192 blk)  ||  z = xb@Ub^T -> z_t (32 blk)
//  P3: conv: in-block softmax(z_t)->rep, circulant MFMA          (384 blk)
//  P4: out = out_pre @ Wp^T + bp  (f32)                          (192 blk)
// ---------------------------------------------------------------------------

typedef __bf16 bf16x8 __attribute__((ext_vector_type(8)));
typedef float  f32x4  __attribute__((ext_vector_type(4)));

#define AS_GLOBAL(p) ((const __attribute__((address_space(1))) unsigned int*)(p))
#define AS_LDS(p)    ((__attribute__((address_space(3))) unsigned int*)(p))

__device__ __forceinline__ void async16(const void* g, void* l) {
    __builtin_amdgcn_global_load_lds(AS_GLOBAL(g), AS_LDS(l), 16, 0, 0);
}

struct bf4 { __bf16 a, b, c, d; };

// ---------------------------------------------------------------------------
__device__ __forceinline__ void grid_barrier(unsigned* arrive, unsigned* gen,
                                             unsigned k)
{
    const int bid = blockIdx.x, tid = threadIdx.x;
    __syncthreads();
    if (bid == 0) {
        if (tid == 0)
            __hip_atomic_store(&arrive[0], k, __ATOMIC_RELEASE,
                               __HIP_MEMORY_SCOPE_AGENT);
        // 256 threads each wait on 2 flags (512 distinct cachelines)
#pragma unroll
        for (int j = 0; j < 2; ++j) {
            unsigned* f = &arrive[tid + j * 256];
            while (__hip_atomic_load(f, __ATOMIC_ACQUIRE,
                                     __HIP_MEMORY_SCOPE_AGENT) < k)
                __builtin_amdgcn_s_sleep(4);
        }
        __syncthreads();
        if (tid == 0)
            __hip_atomic_store(gen, k, __ATOMIC_RELEASE,
                               __HIP_MEMORY_SCOPE_AGENT);
    } else {
        if (tid == 0) {
            __hip_atomic_store(&arrive[bid], k, __ATOMIC_RELEASE,
                               __HIP_MEMORY_SCOPE_AGENT);
            while (__hip_atomic_load(gen, __ATOMIC_ACQUIRE,
                                     __HIP_MEMORY_SCOPE_AGENT) < k)
                __builtin_amdgcn_s_sleep(8);
        }
        __syncthreads();
    }
}

// ---------------------------------------------------------------------------
// bf16 GEMM phase:  C[m][n] = sum_k A[m][k]*Bt[n][k].  BM=128, BK=32.
// MODE 0: bf16 store   MODE 1: f32 + bias   MODE 2: z transposed f32
// ---------------------------------------------------------------------------
template <int BN, int MODE>
__device__ void gemm_phase(char* smem, const __bf16* __restrict__ A,
                           const __bf16* __restrict__ Bt, void* __restrict__ Cout,
                           const float* __restrict__ bias,
                           int K, int ldA, int ldBt, int ldC, int mBase, int nBase)
{
    __bf16* As = (__bf16*)smem;                    // 128 x 32
    __bf16* Bs = (__bf16*)(smem + 128 * 32 * 2);   // BN x 32
    constexpr int WN = BN / 2, NI = WN / 16;
    const int tid = threadIdx.x;
    const int lane = tid & 63, wid = tid >> 6;
    const int lane15 = lane & 15, quad = lane >> 4;
    const int wm = (wid & 1) * 64, wn = (wid >> 1) * WN;

    f32x4 acc[4][NI] = {};

    for (int kb = 0; kb < K; kb += 32) {
        __syncthreads();
#pragma unroll
        for (int c0 = 0; c0 < 512; c0 += 256) {
            int c = c0 + tid, row = c >> 2, slot = c & 3;
            int k8 = slot ^ ((row >> 1) & 3);
            async16(A + (size_t)(mBase + row) * ldA + kb + k8 * 8, As + c * 8);
        }
#pragma unroll
        for (int c0 = 0; c0 < BN * 4; c0 += 256) {
            int c = c0 + tid, row = c >> 2, slot = c & 3;
            int k8 = slot ^ ((row >> 1) & 3);
            async16(Bt + (size_t)(nBase + row) * ldBt + kb + k8 * 8, Bs + c * 8);
        }
        __syncthreads();

        bf16x8 af[4], bv[NI];
#pragma unroll
        for (int mi = 0; mi < 4; ++mi) {
            int row = wm + mi * 16 + lane15;
            af[mi] = *(const bf16x8*)&As[row * 32 + (quad ^ ((row >> 1) & 3)) * 8];
        }
#pragma unroll
        for (int ni = 0; ni < NI; ++ni) {
            int row = wn + ni * 16 + lane15;
            bv[ni] = *(const bf16x8*)&Bs[row * 32 + (quad ^ ((row >> 1) & 3)) * 8];
        }
#pragma unroll
        for (int mi = 0; mi < 4; ++mi)
#pragma unroll
            for (int ni = 0; ni < NI; ++ni)
                acc[mi][ni] = __builtin_amdgcn_mfma_f32_16x16x32_bf16(
                    af[mi], bv[ni], acc[mi][ni], 0, 0, 0);
    }

#pragma unroll
    for (int mi = 0; mi < 4; ++mi)
#pragma unroll
        for (int ni = 0; ni < NI; ++ni)
#pragma unroll
            for (int r = 0; r < 4; ++r) {
                int row = mBase + wm + mi * 16 + quad * 4 + r;
                int col = nBase + wn + ni * 16 + lane15;
                float v = acc[mi][ni][r];
                if (MODE == 0) {
                    ((__bf16*)Cout)[(size_t)row * ldC + col] = (__bf16)v;
                } else if (MODE == 1) {
                    ((float*)Cout)[(size_t)row * ldC + col] = v + bias[col];
                } else {
                    int b = row >> 11;
                    if ((unsigned)(col - b * 12) < 12u)
                        ((float*)Cout)[(size_t)col * 2048 + (row & 2047)] = v;
                }
            }
}

// ---------------------------------------------------------------------------
// Conv phase with in-block softmax.  384 tiles: 128 rows(i) x 64 dd per (b,h).
// smem: rep[8][2056] @0 (32896B) | vt 64x64 @32896 (8192B, aliases red)
//       attn_s[2048] bf16 @41088 (4096B)    total 45184B
// ---------------------------------------------------------------------------
__device__ void conv_phase(char* smem, const float* __restrict__ z_t,
                           const __bf16* __restrict__ VT,
                           __bf16* __restrict__ outp, int bid)
{
    __bf16 (*rep)[2056] = (__bf16(*)[2056])smem;
    __bf16* vt = (__bf16*)(smem + 32896);
    float* red = (float*)(smem + 32896);
    __bf16* attn_s = (__bf16*)(smem + 41088);

    const int tid = threadIdx.x;
    const int lane = tid & 63, wid = tid >> 6;
    const int lane15 = lane & 15, quad = lane >> 4;
    const int bh = bid >> 4, b = bh / 12, h = bh % 12;
    const int m0 = (bid & 15) * 128 + (wid & 1) * 64;
    const int wn = (wid >> 1) * 32;

    // ---- softmax of z_t row -> attn_s (attn/N, bf16) ----
    {
        const float* z = z_t + (size_t)bh * 2048;
        float v[8];
        float m = -1e30f;
#pragma unroll
        for (int j = 0; j < 8; ++j) { v[j] = z[tid + j * 256]; m = fmaxf(m, v[j]); }
#pragma unroll
        for (int off = 32; off; off >>= 1) m = fmaxf(m, __shfl_xor(m, off));
        if (lane == 0) red[wid] = m;
        __syncthreads();
        m = fmaxf(fmaxf(red[0], red[1]), fmaxf(red[2], red[3]));
        __syncthreads();
        float s = 0.f;
#pragma unroll
        for (int j = 0; j < 8; ++j) { v[j] = __expf(v[j] - m); s += v[j]; }
#pragma unroll
        for (int off = 32; off; off >>= 1) s += __shfl_xor(s, off);
        if (lane == 0) red[wid] = s;
        __syncthreads();
        s = red[0] + red[1] + red[2] + red[3];
        float inv = 1.f / (s * 2048.f);
#pragma unroll
        for (int j = 0; j < 8; ++j)
            attn_s[tid + j * 256] = (__bf16)(v[j] * inv);
    }
    __syncthreads();
    // ---- build 8 shift replicas ----
    for (int idx = tid; idx < 8 * 2048; idx += 256) {
        int a = idx >> 11, u = idx & 2047;
        rep[a][u] = attn_s[(u + a) & 2047];
    }

    const __bf16* vsrc = VT + (size_t)h * 64 * 4096 + b * 2048;
    f32x4 acc[4][2] = {};

    for (int kb = 0; kb < 32; ++kb) {
        __syncthreads();
#pragma unroll
        for (int c0 = 0; c0 < 512; c0 += 256) {
            int c = c0 + tid, dd = c >> 3, slot = c & 7;
            int k8 = slot ^ (dd & 7);
            async16(vsrc + (size_t)dd * 4096 + kb * 64 + k8 * 8, vt + c * 8);
        }
        __syncthreads();

#pragma unroll
        for (int ks = 0; ks < 2; ++ks) {
            int kloc = ks * 32 + quad * 8;
            int kglob = kb * 64 + kloc;
            bf16x8 af[4], bv[2];
#pragma unroll
            for (int mi = 0; mi < 4; ++mi) {
                int m = m0 + mi * 16 + lane15;
                int p = (kglob - m) & 2047;
                int al = p & 7;
                af[mi] = *(const bf16x8*)&rep[al][p - al];
            }
#pragma unroll
            for (int ni = 0; ni < 2; ++ni) {
                int dd = wn + ni * 16 + lane15;
                int slot = (kloc >> 3) ^ (dd & 7);
                bv[ni] = *(const bf16x8*)&vt[dd * 64 + slot * 8];
            }
#pragma unroll
            for (int mi = 0; mi < 4; ++mi)
#pragma unroll
                for (int ni = 0; ni < 2; ++ni)
                    acc[mi][ni] = __builtin_amdgcn_mfma_f32_16x16x32_bf16(
                        af[mi], bv[ni], acc[mi][ni], 0, 0, 0);
        }
    }

#pragma unroll
    for (int mi = 0; mi < 4; ++mi)
#pragma unroll
        for (int ni = 0; ni < 2; ++ni)
#pragma unroll
            for (int r = 0; r < 4; ++r) {
                int i = m0 + mi * 16 + quad * 4 + r;
                int dd = wn + ni * 16 + lane15;
                outp[(size_t)(b * 2048 + i) * 768 + h * 64 + dd] =
                    (__bf16)acc[mi][ni][r];
            }
}

// ---------------------------------------------------------------------------
__global__ __launch_bounds__(256, 2)
void mega(const float* __restrict__ x, const float* __restrict__ Wq,
          const float* __restrict__ Wk, const float* __restrict__ Wv,
          const float* __restrict__ Wp, const float* __restrict__ bp,
          float* __restrict__ out,
          unsigned* arrive, unsigned* gen, float* x_avg,
          __bf16* xb, __bf16* Wvb, __bf16* Wpb, __bf16* Ub,
          float* z_t, __bf16* VT, __bf16* out_pre)
{
    __shared__ __attribute__((aligned(16))) char smem[45184];
    const int bid = blockIdx.x, tid = threadIdx.x;

    // ---- P0: converts + column sums ----
    {
        int idx = bid * 256 + tid;   // < 131072
        const float4* xf4 = (const float4*)x;
        bf4* xb4 = (bf4*)xb;
#pragma unroll
        for (int r = 0; r < 6; ++r) {
            float4 v = xf4[idx + r * 131072];
            xb4[idx + r * 131072] = bf4{(__bf16)v.x, (__bf16)v.y, (__bf16)v.z, (__bf16)v.w};
        }
        const float4* wv4 = (const float4*)Wv;  bf4* wvb4 = (bf4*)Wvb;
        const float4* wp4 = (const float4*)Wp;  bf4* wpb4 = (bf4*)Wpb;
#pragma unroll
        for (int r = 0; r < 2; ++r) {
            int i = idx + r * 131072;
            if (i < 147456) {
                float4 v = wv4[i];
                wvb4[i] = bf4{(__bf16)v.x, (__bf16)v.y, (__bf16)v.z, (__bf16)v.w};
                float4 w2 = wp4[i];
                wpb4[i] = bf4{(__bf16)w2.x, (__bf16)w2.y, (__bf16)w2.z, (__bf16)w2.w};
            }
        }
        if (bid < 96) {  // column sums of x
            int c = (bid % 3) * 256 + tid;
            int gb = bid / 3, b = gb >> 4, n0 = (gb & 15) * 128;
            const float* p = x + ((size_t)(b * 2048 + n0)) * 768 + c;
            float s = 0.f;
            for (int i2 = 0; i2 < 128; ++i2) s += p[(size_t)i2 * 768];
            atomicAdd(&x_avg[b * 768 + c], s);
        }
    }
    grid_barrier(arrive, gen, 1);

    // ---- P1: Ub rows (24 blocks); zero pad rows (blocks 24..63) ----
    if (bid < 24) {
        int b = bid / 12, h = bid % 12;
        float* sx = (float*)smem;              // 768 f32
        float* sk = (float*)(smem + 768 * 4);  // 64 f32
        for (int c = tid; c < 768; c += 256) sx[c] = x_avg[b * 768 + c];
        __syncthreads();
        {
            int d = tid >> 2, sub = tid & 3;
            const float* wk = Wk + (size_t)(h * 64 + d) * 768;
            float s = 0.f;
            for (int c = sub; c < 768; c += 4) s += sx[c] * wk[c];
            s += __shfl_down(s, 2);
            s += __shfl_down(s, 1);
            if (sub == 0) sk[d] = s * (0.125f / 2048.f);  // fold SCALE and mean
        }
        __syncthreads();
        for (int c = tid; c < 768; c += 256) {
            float s = 0.f;
#pragma unroll 16
            for (int d2 = 0; d2 < 64; ++d2)
                s += sk[d2] * Wq[(size_t)(h * 64 + d2) * 768 + c];
            Ub[(size_t)bid * 768 + c] = (__bf16)s;
        }
    } else if (bid < 64) {
        for (int c = tid; c < 768; c += 256) Ub[(size_t)bid * 768 + c] = (__bf16)0.f;
    }
    grid_barrier(arrive, gen, 2);

    // ---- P2: VT gemm (192 blk)  ||  z gemm (32 blk) ----
    if (bid < 192) {
        gemm_phase<128, 0>(smem, Wvb, xb, VT, nullptr, 768, 768, 768, 4096,
                           (bid / 32) * 128, (bid % 32) * 128);
    } else if (bid < 224) {
        gemm_phase<64, 2>(smem, xb, Ub, z_t, nullptr, 768, 768, 768, 0,
                          (bid - 192) * 128, 0);
    }
    grid_barrier(arrive, gen, 3);

    // ---- P3: softmax + circulant conv (384 blocks) ----
    if (bid < 384) conv_phase(smem, z_t, VT, out_pre, bid);
    grid_barrier(arrive, gen, 4);

    // ---- P4: out = out_pre @ Wp^T + bp (192 blocks) ----
    if (bid < 192) {
        gemm_phase<128, 1>(smem, out_pre, Wpb, out, bp, 768, 768, 768, 768,
                           (bid / 6) * 128, (bid % 6) * 128);
    }
}

// ---------------------------------------------------------------------------
extern "C" void kernel_launch(void* const* d_in, const int* in_sizes, int n_in,
                              void* d_out, int out_size, void* d_ws, size_t ws_size,
                              hipStream_t stream)
{
    (void)in_sizes; (void)n_in; (void)out_size; (void)ws_size;
    const float* x  = (const float*)d_in[0];
    const float* Wq = (const float*)d_in[1];
    const float* Wk = (const float*)d_in[2];
    const float* Wv = (const float*)d_in[3];
    const float* Wp = (const float*)d_in[4];
    const float* bp = (const float*)d_in[5];

    char* w = (char*)d_ws;
    auto alloc = [&](size_t bytes) {
        char* p = w; w += (bytes + 255) & ~(size_t)255; return p;
    };
    // ctl: arrive[512] | gen | pad | x_avg[1536]
    unsigned* ctl   = (unsigned*)alloc(2560 + 6144);
    __bf16* xb      = (__bf16*)alloc((size_t)4096 * 768 * 2);
    __bf16* Wvb     = (__bf16*)alloc((size_t)768 * 768 * 2);
    __bf16* Wpb     = (__bf16*)alloc((size_t)768 * 768 * 2);
    __bf16* Ub      = (__bf16*)alloc((size_t)64 * 768 * 2);
    float*  z_t     = (float*) alloc((size_t)24 * 2048 * 4);
    __bf16* VT      = (__bf16*)alloc((size_t)768 * 4096 * 2);
    __bf16* out_pre = (__bf16*)alloc((size_t)4096 * 768 * 2);

    unsigned* arrive = ctl;
    unsigned* gen    = ctl + 512;
    float*    x_avg  = (float*)((char*)ctl + 2560);

    // zero barrier flags + gen + x_avg every call (graph-safe)
    hipMemsetAsync(ctl, 0, 2560 + 6144, stream);

    mega<<<512, 256, 0, stream>>>(x, Wq, Wk, Wv, Wp, bp, (float*)d_out,
                                  arrive, gen, x_avg, xb, Wvb, Wpb, Ub,
                                  z_t, VT, out_pre);
}

// Round 4
// 171.432 us; speedup vs baseline: 4.7772x; 4.7772x over previous
//
#include <hip/hip_runtime.h>

// ---------------------------------------------------------------------------
// AveragedKeyCircularConvolutionalAttention  (B=2, N=2048, C=768, h=12, d=64)
// 5-dispatch pipeline (mega-kernel grid barriers cost 60-150us each on
// gfx950 -- R2/R3 post-mortems: same-line RMW contention + acquire-poll
// L2-invalidation storms. Multi-kernel is the cheaper sync).
//
//  D1 k_prep : x,Wv,Wp -> bf16 ; x column-sum partials -> x_part  (512 blk)
//  D2 k_ub   : Ub = SCALE/2048 * (colsum(x)@Wk^T) @ Wq rows       (64 blk)
//  D3 k_gemms: VT = (x@Wv^T)^T (192 blk) || z_t = (xb@Ub^T)^T (32 blk)
//  D4 k_conv : in-block softmax(z_t) + circulant MFMA -> out_pre  (384 blk)
//  D5 k_out  : out = out_pre @ Wp^T + bp  (f32)                   (192 blk)
// ---------------------------------------------------------------------------

typedef __bf16 bf16x8 __attribute__((ext_vector_type(8)));
typedef float  f32x4  __attribute__((ext_vector_type(4)));

#define AS_GLOBAL(p) ((const __attribute__((address_space(1))) unsigned int*)(p))
#define AS_LDS(p)    ((__attribute__((address_space(3))) unsigned int*)(p))

__device__ __forceinline__ void async16(const void* g, void* l) {
    __builtin_amdgcn_global_load_lds(AS_GLOBAL(g), AS_LDS(l), 16, 0, 0);
}

struct bf4 { __bf16 a, b, c, d; };

// ---------------------------------------------------------------------------
// bf16 GEMM tile:  C[m][n] = sum_k A[m][k]*Bt[n][k].  BM=128, BK=32.
// MODE 0: bf16 store   MODE 1: f32 + bias   MODE 2: z transposed f32
// ---------------------------------------------------------------------------
template <int BN, int MODE>
__device__ void gemm_phase(char* smem, const __bf16* __restrict__ A,
                           const __bf16* __restrict__ Bt, void* __restrict__ Cout,
                           const float* __restrict__ bias,
                           int K, int ldA, int ldBt, int ldC, int mBase, int nBase)
{
    __bf16* As = (__bf16*)smem;                    // 128 x 32
    __bf16* Bs = (__bf16*)(smem + 128 * 32 * 2);   // BN x 32
    constexpr int WN = BN / 2, NI = WN / 16;
    const int tid = threadIdx.x;
    const int lane = tid & 63, wid = tid >> 6;
    const int lane15 = lane & 15, quad = lane >> 4;
    const int wm = (wid & 1) * 64, wn = (wid >> 1) * WN;

    f32x4 acc[4][NI] = {};

    for (int kb = 0; kb < K; kb += 32) {
        __syncthreads();
#pragma unroll
        for (int c0 = 0; c0 < 512; c0 += 256) {
            int c = c0 + tid, row = c >> 2, slot = c & 3;
            int k8 = slot ^ ((row >> 1) & 3);
            async16(A + (size_t)(mBase + row) * ldA + kb + k8 * 8, As + c * 8);
        }
#pragma unroll
        for (int c0 = 0; c0 < BN * 4; c0 += 256) {
            int c = c0 + tid, row = c >> 2, slot = c & 3;
            int k8 = slot ^ ((row >> 1) & 3);
            async16(Bt + (size_t)(nBase + row) * ldBt + kb + k8 * 8, Bs + c * 8);
        }
        __syncthreads();

        bf16x8 af[4], bv[NI];
#pragma unroll
        for (int mi = 0; mi < 4; ++mi) {
            int row = wm + mi * 16 + lane15;
            af[mi] = *(const bf16x8*)&As[row * 32 + (quad ^ ((row >> 1) & 3)) * 8];
        }
#pragma unroll
        for (int ni = 0; ni < NI; ++ni) {
            int row = wn + ni * 16 + lane15;
            bv[ni] = *(const bf16x8*)&Bs[row * 32 + (quad ^ ((row >> 1) & 3)) * 8];
        }
#pragma unroll
        for (int mi = 0; mi < 4; ++mi)
#pragma unroll
            for (int ni = 0; ni < NI; ++ni)
                acc[mi][ni] = __builtin_amdgcn_mfma_f32_16x16x32_bf16(
                    af[mi], bv[ni], acc[mi][ni], 0, 0, 0);
    }

#pragma unroll
    for (int mi = 0; mi < 4; ++mi)
#pragma unroll
        for (int ni = 0; ni < NI; ++ni)
#pragma unroll
            for (int r = 0; r < 4; ++r) {
                int row = mBase + wm + mi * 16 + quad * 4 + r;
                int col = nBase + wn + ni * 16 + lane15;
                float v = acc[mi][ni][r];
                if (MODE == 0) {
                    ((__bf16*)Cout)[(size_t)row * ldC + col] = (__bf16)v;
                } else if (MODE == 1) {
                    ((float*)Cout)[(size_t)row * ldC + col] = v + bias[col];
                } else {
                    int b = row >> 11;
                    if ((unsigned)(col - b * 12) < 12u)
                        ((float*)Cout)[(size_t)col * 2048 + (row & 2047)] = v;
                }
            }
}

// ---------------------------------------------------------------------------
// D1: converts + column-sum partials (no atomics; x_part[(b*16+g)*768+c])
// ---------------------------------------------------------------------------
__global__ __launch_bounds__(256)
void k_prep(const float* __restrict__ x, const float* __restrict__ Wv,
            const float* __restrict__ Wp,
            __bf16* __restrict__ xb, __bf16* __restrict__ Wvb,
            __bf16* __restrict__ Wpb, float* __restrict__ x_part)
{
    const int bid = blockIdx.x, tid = threadIdx.x;
    int idx = bid * 256 + tid;   // < 131072
    const float4* xf4 = (const float4*)x;
    bf4* xb4 = (bf4*)xb;
#pragma unroll
    for (int r = 0; r < 6; ++r) {
        float4 v = xf4[idx + r * 131072];
        xb4[idx + r * 131072] = bf4{(__bf16)v.x, (__bf16)v.y, (__bf16)v.z, (__bf16)v.w};
    }
    const float4* wv4 = (const float4*)Wv;  bf4* wvb4 = (bf4*)Wvb;
    const float4* wp4 = (const float4*)Wp;  bf4* wpb4 = (bf4*)Wpb;
#pragma unroll
    for (int r = 0; r < 2; ++r) {
        int i = idx + r * 131072;
        if (i < 147456) {
            float4 v = wv4[i];
            wvb4[i] = bf4{(__bf16)v.x, (__bf16)v.y, (__bf16)v.z, (__bf16)v.w};
            float4 w2 = wp4[i];
            wpb4[i] = bf4{(__bf16)w2.x, (__bf16)w2.y, (__bf16)w2.z, (__bf16)w2.w};
        }
    }
    if (bid < 96) {  // column-sum partials over 128-row groups
        int c = (bid % 3) * 256 + tid;
        int gb = bid / 3, b = gb >> 4, g = gb & 15;
        const float* p = x + ((size_t)(b * 2048 + g * 128)) * 768 + c;
        float s = 0.f;
        for (int i2 = 0; i2 < 128; ++i2) s += p[(size_t)i2 * 768];
        x_part[(size_t)(b * 16 + g) * 768 + c] = s;
    }
}

// ---------------------------------------------------------------------------
// D2: Ub rows (24 real + 40 zero-pad).  One block per bh.
// ---------------------------------------------------------------------------
__global__ __launch_bounds__(256)
void k_ub(const float* __restrict__ x_part, const float* __restrict__ Wk,
          const float* __restrict__ Wq, __bf16* __restrict__ Ub)
{
    const int bid = blockIdx.x, tid = threadIdx.x;
    if (bid >= 24) {  // zero pad rows for the BN=64 z-GEMM
        for (int c = tid; c < 768; c += 256) Ub[(size_t)bid * 768 + c] = (__bf16)0.f;
        return;
    }
    __shared__ float sx[768];
    __shared__ float sk[64];
    int b = bid / 12, h = bid % 12;
    for (int c = tid; c < 768; c += 256) {
        float s = 0.f;
#pragma unroll
        for (int g = 0; g < 16; ++g)
            s += x_part[(size_t)(b * 16 + g) * 768 + c];
        sx[c] = s;
    }
    __syncthreads();
    {
        int d = tid >> 2, sub = tid & 3;
        const float* wk = Wk + (size_t)(h * 64 + d) * 768;
        float s = 0.f;
        for (int c = sub; c < 768; c += 4) s += sx[c] * wk[c];
        s += __shfl_down(s, 2);
        s += __shfl_down(s, 1);
        if (sub == 0) sk[d] = s * (0.125f / 2048.f);  // fold SCALE and mean
    }
    __syncthreads();
    for (int c = tid; c < 768; c += 256) {
        float s = 0.f;
#pragma unroll 16
        for (int d2 = 0; d2 < 64; ++d2)
            s += sk[d2] * Wq[(size_t)(h * 64 + d2) * 768 + c];
        Ub[(size_t)bid * 768 + c] = (__bf16)s;
    }
}

// ---------------------------------------------------------------------------
// D3: VT gemm (blocks 0..191)  ||  z gemm (blocks 192..223)
// ---------------------------------------------------------------------------
__global__ __launch_bounds__(256, 2)
void k_gemms(const __bf16* __restrict__ xb, const __bf16* __restrict__ Wvb,
             const __bf16* __restrict__ Ub, __bf16* __restrict__ VT,
             float* __restrict__ z_t)
{
    __shared__ __attribute__((aligned(16))) char smem[16384];
    const int bid = blockIdx.x;
    if (bid < 192) {
        gemm_phase<128, 0>(smem, Wvb, xb, VT, nullptr, 768, 768, 768, 4096,
                           (bid / 32) * 128, (bid % 32) * 128);
    } else {
        gemm_phase<64, 2>(smem, xb, Ub, z_t, nullptr, 768, 768, 768, 0,
                          (bid - 192) * 128, 0);
    }
}

// ---------------------------------------------------------------------------
// D4: conv with in-block softmax.  384 tiles: 128 rows(i) x 64 dd per (b,h).
// smem: rep[8][2056] @0 | vt 64x64 @32896 (aliases red) | attn_s @41088
// ---------------------------------------------------------------------------
__global__ __launch_bounds__(256, 2)
void k_conv(const float* __restrict__ z_t, const __bf16* __restrict__ VT,
            __bf16* __restrict__ outp)
{
    __shared__ __attribute__((aligned(16))) char smem[45184];
    __bf16 (*rep)[2056] = (__bf16(*)[2056])smem;
    __bf16* vt = (__bf16*)(smem + 32896);
    float* red = (float*)(smem + 32896);
    __bf16* attn_s = (__bf16*)(smem + 41088);

    const int bid = blockIdx.x, tid = threadIdx.x;
    const int lane = tid & 63, wid = tid >> 6;
    const int lane15 = lane & 15, quad = lane >> 4;
    const int bh = bid >> 4, b = bh / 12, h = bh % 12;
    const int m0 = (bid & 15) * 128 + (wid & 1) * 64;
    const int wn = (wid >> 1) * 32;

    // softmax of z_t row -> attn_s (attn/N, bf16)
    {
        const float* z = z_t + (size_t)bh * 2048;
        float v[8];
        float m = -1e30f;
#pragma unroll
        for (int j = 0; j < 8; ++j) { v[j] = z[tid + j * 256]; m = fmaxf(m, v[j]); }
#pragma unroll
        for (int off = 32; off; off >>= 1) m = fmaxf(m, __shfl_xor(m, off));
        if (lane == 0) red[wid] = m;
        __syncthreads();
        m = fmaxf(fmaxf(red[0], red[1]), fmaxf(red[2], red[3]));
        __syncthreads();
        float s = 0.f;
#pragma unroll
        for (int j = 0; j < 8; ++j) { v[j] = __expf(v[j] - m); s += v[j]; }
#pragma unroll
        for (int off = 32; off; off >>= 1) s += __shfl_xor(s, off);
        if (lane == 0) red[wid] = s;
        __syncthreads();
        s = red[0] + red[1] + red[2] + red[3];
        float inv = 1.f / (s * 2048.f);
#pragma unroll
        for (int j = 0; j < 8; ++j)
            attn_s[tid + j * 256] = (__bf16)(v[j] * inv);
    }
    __syncthreads();
    // build 8 shift replicas
    for (int idx = tid; idx < 8 * 2048; idx += 256) {
        int a = idx >> 11, u = idx & 2047;
        rep[a][u] = attn_s[(u + a) & 2047];
    }

    const __bf16* vsrc = VT + (size_t)h * 64 * 4096 + b * 2048;
    f32x4 acc[4][2] = {};

    for (int kb = 0; kb < 32; ++kb) {
        __syncthreads();
#pragma unroll
        for (int c0 = 0; c0 < 512; c0 += 256) {
            int c = c0 + tid, dd = c >> 3, slot = c & 7;
            int k8 = slot ^ (dd & 7);
            async16(vsrc + (size_t)dd * 4096 + kb * 64 + k8 * 8, vt + c * 8);
        }
        __syncthreads();

#pragma unroll
        for (int ks = 0; ks < 2; ++ks) {
            int kloc = ks * 32 + quad * 8;
            int kglob = kb * 64 + kloc;
            bf16x8 af[4], bv[2];
#pragma unroll
            for (int mi = 0; mi < 4; ++mi) {
                int m = m0 + mi * 16 + lane15;
                int p = (kglob - m) & 2047;
                int al = p & 7;
                af[mi] = *(const bf16x8*)&rep[al][p - al];
            }
#pragma unroll
            for (int ni = 0; ni < 2; ++ni) {
                int dd = wn + ni * 16 + lane15;
                int slot = (kloc >> 3) ^ (dd & 7);
                bv[ni] = *(const bf16x8*)&vt[dd * 64 + slot * 8];
            }
#pragma unroll
            for (int mi = 0; mi < 4; ++mi)
#pragma unroll
                for (int ni = 0; ni < 2; ++ni)
                    acc[mi][ni] = __builtin_amdgcn_mfma_f32_16x16x32_bf16(
                        af[mi], bv[ni], acc[mi][ni], 0, 0, 0);
        }
    }

#pragma unroll
    for (int mi = 0; mi < 4; ++mi)
#pragma unroll
        for (int ni = 0; ni < 2; ++ni)
#pragma unroll
            for (int r = 0; r < 4; ++r) {
                int i = m0 + mi * 16 + quad * 4 + r;
                int dd = wn + ni * 16 + lane15;
                outp[(size_t)(b * 2048 + i) * 768 + h * 64 + dd] =
                    (__bf16)acc[mi][ni][r];
            }
}

// ---------------------------------------------------------------------------
// D5: out = out_pre @ Wp^T + bp  (f32)
// ---------------------------------------------------------------------------
__global__ __launch_bounds__(256, 2)
void k_out(const __bf16* __restrict__ out_pre, const __bf16* __restrict__ Wpb,
           const float* __restrict__ bp, float* __restrict__ out)
{
    __shared__ __attribute__((aligned(16))) char smem[16384];
    const int bid = blockIdx.x;
    gemm_phase<128, 1>(smem, out_pre, Wpb, out, bp, 768, 768, 768, 768,
                       (bid / 6) * 128, (bid % 6) * 128);
}

// ---------------------------------------------------------------------------
extern "C" void kernel_launch(void* const* d_in, const int* in_sizes, int n_in,
                              void* d_out, int out_size, void* d_ws, size_t ws_size,
                              hipStream_t stream)
{
    (void)in_sizes; (void)n_in; (void)out_size; (void)ws_size;
    const float* x  = (const float*)d_in[0];
    const float* Wq = (const float*)d_in[1];
    const float* Wk = (const float*)d_in[2];
    const float* Wv = (const float*)d_in[3];
    const float* Wp = (const float*)d_in[4];
    const float* bp = (const float*)d_in[5];

    char* w = (char*)d_ws;
    auto alloc = [&](size_t bytes) {
        char* p = w; w += (bytes + 255) & ~(size_t)255; return p;
    };
    float*  x_part  = (float*) alloc((size_t)32 * 768 * 4);
    __bf16* xb      = (__bf16*)alloc((size_t)4096 * 768 * 2);
    __bf16* Wvb     = (__bf16*)alloc((size_t)768 * 768 * 2);
    __bf16* Wpb     = (__bf16*)alloc((size_t)768 * 768 * 2);
    __bf16* Ub      = (__bf16*)alloc((size_t)64 * 768 * 2);
    float*  z_t     = (float*) alloc((size_t)24 * 2048 * 4);
    __bf16* VT      = (__bf16*)alloc((size_t)768 * 4096 * 2);
    __bf16* out_pre = (__bf16*)alloc((size_t)4096 * 768 * 2);

    k_prep <<<512, 256, 0, stream>>>(x, Wv, Wp, xb, Wvb, Wpb, x_part);
    k_ub   <<<64,  256, 0, stream>>>(x_part, Wk, Wq, Ub);
    k_gemms<<<224, 256, 0, stream>>>(xb, Wvb, Ub, VT, z_t);
    k_conv <<<384, 256, 0, stream>>>(z_t, VT, out_pre);
    k_out  <<<192, 256, 0, stream>>>(out_pre, Wpb, bp, (float*)d_out);
}

// Round 5
// 163.877 us; speedup vs baseline: 4.9974x; 1.0461x over previous
//
#include <hip/hip_runtime.h>

// ---------------------------------------------------------------------------
// AveragedKeyCircularConvolutionalAttention  (B=2, N=2048, C=768, h=12, d=64)
// 5-dispatch pipeline. R5: all MFMA K-loops are single-barrier double-buffered
// (at 1-1.5 blocks/CU the old 2-barrier loop exposed full global->LDS latency
// every iteration; dbuf overlaps stage k+1 with compute k).
//
//  D1 k_prep : x,Wv,Wp -> bf16 ; x column-sum partials -> x_part  (512 blk)
//  D2 k_ub   : Ub = SCALE/2048 * (colsum(x)@Wk^T) @ Wq rows       (64 blk)
//  D3 k_gemms: VT = (x@Wv^T)^T (192 blk) || z_t = (xb@Ub^T)^T (32 blk)
//  D4 k_conv : in-block softmax(z_t) + circulant MFMA -> out_pre  (384 blk)
//  D5 k_out  : out = out_pre @ Wp^T + bp  (f32)                   (192 blk)
// ---------------------------------------------------------------------------

typedef __bf16 bf16x8 __attribute__((ext_vector_type(8)));
typedef float  f32x4  __attribute__((ext_vector_type(4)));

#define AS_GLOBAL(p) ((const __attribute__((address_space(1))) unsigned int*)(p))
#define AS_LDS(p)    ((__attribute__((address_space(3))) unsigned int*)(p))

__device__ __forceinline__ void async16(const void* g, void* l) {
    __builtin_amdgcn_global_load_lds(AS_GLOBAL(g), AS_LDS(l), 16, 0, 0);
}

struct bf4 { __bf16 a, b, c, d; };

// ---------------------------------------------------------------------------
// bf16 GEMM tile:  C[m][n] = sum_k A[m][k]*Bt[n][k].  BM=128, BK=32, dbuf.
// MODE 0: bf16 store   MODE 1: f32 + bias   MODE 2: z transposed f32
// smem layout: [As0|Bs0|As1|Bs1], stride = (128+BN)*32*2 bytes.
// ---------------------------------------------------------------------------
template <int BN, int MODE>
__device__ void gemm_phase(char* smem, const __bf16* __restrict__ A,
                           const __bf16* __restrict__ Bt, void* __restrict__ Cout,
                           const float* __restrict__ bias,
                           int K, int ldA, int ldBt, int ldC, int mBase, int nBase)
{
    constexpr int STRIDE = (128 + BN) * 32 * 2;   // bytes per buffer pair
    constexpr int WN = BN / 2, NI = WN / 16;
    const int tid = threadIdx.x;
    const int lane = tid & 63, wid = tid >> 6;
    const int lane15 = lane & 15, quad = lane >> 4;
    const int wm = (wid & 1) * 64, wn = (wid >> 1) * WN;

    auto stage = [&](int kb, int buf) {
        __bf16* As = (__bf16*)(smem + buf * STRIDE);
        __bf16* Bs = As + 128 * 32;
#pragma unroll
        for (int c0 = 0; c0 < 512; c0 += 256) {
            int c = c0 + tid, row = c >> 2, slot = c & 3;
            int k8 = slot ^ ((row >> 1) & 3);
            async16(A + (size_t)(mBase + row) * ldA + kb + k8 * 8, As + c * 8);
        }
#pragma unroll
        for (int c0 = 0; c0 < BN * 4; c0 += 256) {
            int c = c0 + tid, row = c >> 2, slot = c & 3;
            int k8 = slot ^ ((row >> 1) & 3);
            async16(Bt + (size_t)(nBase + row) * ldBt + kb + k8 * 8, Bs + c * 8);
        }
    };

    f32x4 acc[4][NI] = {};
    const int nk = K >> 5;

    stage(0, 0);
    for (int ki = 0; ki < nk; ++ki) {
        __syncthreads();                       // drains stage ki (vmcnt(0))
        if (ki + 1 < nk) stage((ki + 1) << 5, (ki + 1) & 1);

        __bf16* As = (__bf16*)(smem + (ki & 1) * STRIDE);
        __bf16* Bs = As + 128 * 32;
        bf16x8 af[4], bv[NI];
#pragma unroll
        for (int mi = 0; mi < 4; ++mi) {
            int row = wm + mi * 16 + lane15;
            af[mi] = *(const bf16x8*)&As[row * 32 + (quad ^ ((row >> 1) & 3)) * 8];
        }
#pragma unroll
        for (int ni = 0; ni < NI; ++ni) {
            int row = wn + ni * 16 + lane15;
            bv[ni] = *(const bf16x8*)&Bs[row * 32 + (quad ^ ((row >> 1) & 3)) * 8];
        }
#pragma unroll
        for (int mi = 0; mi < 4; ++mi)
#pragma unroll
            for (int ni = 0; ni < NI; ++ni)
                acc[mi][ni] = __builtin_amdgcn_mfma_f32_16x16x32_bf16(
                    af[mi], bv[ni], acc[mi][ni], 0, 0, 0);
    }

#pragma unroll
    for (int mi = 0; mi < 4; ++mi)
#pragma unroll
        for (int ni = 0; ni < NI; ++ni)
#pragma unroll
            for (int r = 0; r < 4; ++r) {
                int row = mBase + wm + mi * 16 + quad * 4 + r;
                int col = nBase + wn + ni * 16 + lane15;
                float v = acc[mi][ni][r];
                if (MODE == 0) {
                    ((__bf16*)Cout)[(size_t)row * ldC + col] = (__bf16)v;
                } else if (MODE == 1) {
                    ((float*)Cout)[(size_t)row * ldC + col] = v + bias[col];
                } else {
                    int b = row >> 11;
                    if ((unsigned)(col - b * 12) < 12u)
                        ((float*)Cout)[(size_t)col * 2048 + (row & 2047)] = v;
                }
            }
}

// ---------------------------------------------------------------------------
// D1: converts + column-sum partials
// ---------------------------------------------------------------------------
__global__ __launch_bounds__(256)
void k_prep(const float* __restrict__ x, const float* __restrict__ Wv,
            const float* __restrict__ Wp,
            __bf16* __restrict__ xb, __bf16* __restrict__ Wvb,
            __bf16* __restrict__ Wpb, float* __restrict__ x_part)
{
    const int bid = blockIdx.x, tid = threadIdx.x;
    int idx = bid * 256 + tid;   // < 131072
    const float4* xf4 = (const float4*)x;
    bf4* xb4 = (bf4*)xb;
#pragma unroll
    for (int r = 0; r < 6; ++r) {
        float4 v = xf4[idx + r * 131072];
        xb4[idx + r * 131072] = bf4{(__bf16)v.x, (__bf16)v.y, (__bf16)v.z, (__bf16)v.w};
    }
    const float4* wv4 = (const float4*)Wv;  bf4* wvb4 = (bf4*)Wvb;
    const float4* wp4 = (const float4*)Wp;  bf4* wpb4 = (bf4*)Wpb;
#pragma unroll
    for (int r = 0; r < 2; ++r) {
        int i = idx + r * 131072;
        if (i < 147456) {
            float4 v = wv4[i];
            wvb4[i] = bf4{(__bf16)v.x, (__bf16)v.y, (__bf16)v.z, (__bf16)v.w};
            float4 w2 = wp4[i];
            wpb4[i] = bf4{(__bf16)w2.x, (__bf16)w2.y, (__bf16)w2.z, (__bf16)w2.w};
        }
    }
    if (bid < 96) {  // column-sum partials over 128-row groups
        int c = (bid % 3) * 256 + tid;
        int gb = bid / 3, b = gb >> 4, g = gb & 15;
        const float* p = x + ((size_t)(b * 2048 + g * 128)) * 768 + c;
        float s = 0.f;
        for (int i2 = 0; i2 < 128; ++i2) s += p[(size_t)i2 * 768];
        x_part[(size_t)(b * 16 + g) * 768 + c] = s;
    }
}

// ---------------------------------------------------------------------------
// D2: Ub rows (24 real + 40 zero-pad).  One block per bh.
// ---------------------------------------------------------------------------
__global__ __launch_bounds__(256)
void k_ub(const float* __restrict__ x_part, const float* __restrict__ Wk,
          const float* __restrict__ Wq, __bf16* __restrict__ Ub)
{
    const int bid = blockIdx.x, tid = threadIdx.x;
    if (bid >= 24) {
        for (int c = tid; c < 768; c += 256) Ub[(size_t)bid * 768 + c] = (__bf16)0.f;
        return;
    }
    __shared__ float sx[768];
    __shared__ float sk[64];
    int b = bid / 12, h = bid % 12;
    for (int c = tid; c < 768; c += 256) {
        float s = 0.f;
#pragma unroll
        for (int g = 0; g < 16; ++g)
            s += x_part[(size_t)(b * 16 + g) * 768 + c];
        sx[c] = s;
    }
    __syncthreads();
    {
        int d = tid >> 2, sub = tid & 3;
        const float* wk = Wk + (size_t)(h * 64 + d) * 768;
        float s = 0.f;
        for (int c = sub; c < 768; c += 4) s += sx[c] * wk[c];
        s += __shfl_down(s, 2);
        s += __shfl_down(s, 1);
        if (sub == 0) sk[d] = s * (0.125f / 2048.f);
    }
    __syncthreads();
    for (int c = tid; c < 768; c += 256) {
        float s = 0.f;
#pragma unroll 16
        for (int d2 = 0; d2 < 64; ++d2)
            s += sk[d2] * Wq[(size_t)(h * 64 + d2) * 768 + c];
        Ub[(size_t)bid * 768 + c] = (__bf16)s;
    }
}

// ---------------------------------------------------------------------------
// D3: VT gemm (blocks 0..191)  ||  z gemm (blocks 192..223)
// ---------------------------------------------------------------------------
__global__ __launch_bounds__(256, 2)
void k_gemms(const __bf16* __restrict__ xb, const __bf16* __restrict__ Wvb,
             const __bf16* __restrict__ Ub, __bf16* __restrict__ VT,
             float* __restrict__ z_t)
{
    __shared__ __attribute__((aligned(16))) char smem[32768];
    const int bid = blockIdx.x;
    if (bid < 192) {
        gemm_phase<128, 0>(smem, Wvb, xb, VT, nullptr, 768, 768, 768, 4096,
                           (bid / 32) * 128, (bid % 32) * 128);
    } else {
        gemm_phase<64, 2>(smem, xb, Ub, z_t, nullptr, 768, 768, 768, 0,
                          (bid - 192) * 128, 0);
    }
}

// ---------------------------------------------------------------------------
// D4: conv with in-block softmax, dbuf V-tile.
// smem: rep[8][2056] @0 (32896) | vt0 @32896 (8192, aliases red) |
//       vt1 @41088 (8192) | attn_s @49280 (4096)   total 53376
// ---------------------------------------------------------------------------
__global__ __launch_bounds__(256, 2)
void k_conv(const float* __restrict__ z_t, const __bf16* __restrict__ VT,
            __bf16* __restrict__ outp)
{
    __shared__ __attribute__((aligned(16))) char smem[53376];
    __bf16 (*rep)[2056] = (__bf16(*)[2056])smem;
    float* red = (float*)(smem + 32896);
    __bf16* attn_s = (__bf16*)(smem + 49280);

    const int bid = blockIdx.x, tid = threadIdx.x;
    const int lane = tid & 63, wid = tid >> 6;
    const int lane15 = lane & 15, quad = lane >> 4;
    const int bh = bid >> 4, b = bh / 12, h = bh % 12;
    const int m0 = (bid & 15) * 128 + (wid & 1) * 64;
    const int wn = (wid >> 1) * 32;

    // softmax of z_t row -> attn_s (attn/N, bf16)
    {
        const float* z = z_t + (size_t)bh * 2048;
        float v[8];
        float m = -1e30f;
#pragma unroll
        for (int j = 0; j < 8; ++j) { v[j] = z[tid + j * 256]; m = fmaxf(m, v[j]); }
#pragma unroll
        for (int off = 32; off; off >>= 1) m = fmaxf(m, __shfl_xor(m, off));
        if (lane == 0) red[wid] = m;
        __syncthreads();
        m = fmaxf(fmaxf(red[0], red[1]), fmaxf(red[2], red[3]));
        __syncthreads();
        float s = 0.f;
#pragma unroll
        for (int j = 0; j < 8; ++j) { v[j] = __expf(v[j] - m); s += v[j]; }
#pragma unroll
        for (int off = 32; off; off >>= 1) s += __shfl_xor(s, off);
        if (lane == 0) red[wid] = s;
        __syncthreads();
        s = red[0] + red[1] + red[2] + red[3];
        float inv = 1.f / (s * 2048.f);
#pragma unroll
        for (int j = 0; j < 8; ++j)
            attn_s[tid + j * 256] = (__bf16)(v[j] * inv);
    }
    __syncthreads();
    // build 8 shift replicas
    for (int idx = tid; idx < 8 * 2048; idx += 256) {
        int a = idx >> 11, u = idx & 2047;
        rep[a][u] = attn_s[(u + a) & 2047];
    }

    const __bf16* vsrc = VT + (size_t)h * 64 * 4096 + b * 2048;

    auto stage = [&](int kb, int buf) {
        __bf16* vt = (__bf16*)(smem + 32896 + buf * 8192);
#pragma unroll
        for (int c0 = 0; c0 < 512; c0 += 256) {
            int c = c0 + tid, dd = c >> 3, slot = c & 7;
            int k8 = slot ^ (dd & 7);
            async16(vsrc + (size_t)dd * 4096 + kb * 64 + k8 * 8, vt + c * 8);
        }
    };

    f32x4 acc[4][2] = {};
    stage(0, 0);
    for (int kb = 0; kb < 32; ++kb) {
        __syncthreads();                      // drains stage kb; rep ready too
        if (kb + 1 < 32) stage(kb + 1, (kb + 1) & 1);
        __bf16* vt = (__bf16*)(smem + 32896 + (kb & 1) * 8192);

#pragma unroll
        for (int ks = 0; ks < 2; ++ks) {
            int kloc = ks * 32 + quad * 8;
            int kglob = kb * 64 + kloc;
            bf16x8 af[4], bv[2];
#pragma unroll
            for (int mi = 0; mi < 4; ++mi) {
                int m = m0 + mi * 16 + lane15;
                int p = (kglob - m) & 2047;
                int al = p & 7;
                af[mi] = *(const bf16x8*)&rep[al][p - al];
            }
#pragma unroll
            for (int ni = 0; ni < 2; ++ni) {
                int dd = wn + ni * 16 + lane15;
                int slot = (kloc >> 3) ^ (dd & 7);
                bv[ni] = *(const bf16x8*)&vt[dd * 64 + slot * 8];
            }
#pragma unroll
            for (int mi = 0; mi < 4; ++mi)
#pragma unroll
                for (int ni = 0; ni < 2; ++ni)
                    acc[mi][ni] = __builtin_amdgcn_mfma_f32_16x16x32_bf16(
                        af[mi], bv[ni], acc[mi][ni], 0, 0, 0);
        }
    }

#pragma unroll
    for (int mi = 0; mi < 4; ++mi)
#pragma unroll
        for (int ni = 0; ni < 2; ++ni)
#pragma unroll
            for (int r = 0; r < 4; ++r) {
                int i = m0 + mi * 16 + quad * 4 + r;
                int dd = wn + ni * 16 + lane15;
                outp[(size_t)(b * 2048 + i) * 768 + h * 64 + dd] =
                    (__bf16)acc[mi][ni][r];
            }
}

// ---------------------------------------------------------------------------
// D5: out = out_pre @ Wp^T + bp  (f32)
// ---------------------------------------------------------------------------
__global__ __launch_bounds__(256, 2)
void k_out(const __bf16* __restrict__ out_pre, const __bf16* __restrict__ Wpb,
           const float* __restrict__ bp, float* __restrict__ out)
{
    __shared__ __attribute__((aligned(16))) char smem[32768];
    const int bid = blockIdx.x;
    gemm_phase<128, 1>(smem, out_pre, Wpb, out, bp, 768, 768, 768, 768,
                       (bid / 6) * 128, (bid % 6) * 128);
}

// ---------------------------------------------------------------------------
extern "C" void kernel_launch(void* const* d_in, const int* in_sizes, int n_in,
                              void* d_out, int out_size, void* d_ws, size_t ws_size,
                              hipStream_t stream)
{
    (void)in_sizes; (void)n_in; (void)out_size; (void)ws_size;
    const float* x  = (const float*)d_in[0];
    const float* Wq = (const float*)d_in[1];
    const float* Wk = (const float*)d_in[2];
    const float* Wv = (const float*)d_in[3];
    const float* Wp = (const float*)d_in[4];
    const float* bp = (const float*)d_in[5];

    char* w = (char*)d_ws;
    auto alloc = [&](size_t bytes) {
        char* p = w; w += (bytes + 255) & ~(size_t)255; return p;
    };
    float*  x_part  = (float*) alloc((size_t)32 * 768 * 4);
    __bf16* xb      = (__bf16*)alloc((size_t)4096 * 768 * 2);
    __bf16* Wvb     = (__bf16*)alloc((size_t)768 * 768 * 2);
    __bf16* Wpb     = (__bf16*)alloc((size_t)768 * 768 * 2);
    __bf16* Ub      = (__bf16*)alloc((size_t)64 * 768 * 2);
    float*  z_t     = (float*) alloc((size_t)24 * 2048 * 4);
    __bf16* VT      = (__bf16*)alloc((size_t)768 * 4096 * 2);
    __bf16* out_pre = (__bf16*)alloc((size_t)4096 * 768 * 2);

    k_prep <<<512, 256, 0, stream>>>(x, Wv, Wp, xb, Wvb, Wpb, x_part);
    k_ub   <<<64,  256, 0, stream>>>(x_part, Wk, Wq, Ub);
    k_gemms<<<224, 256, 0, stream>>>(xb, Wvb, Ub, VT, z_t);
    k_conv <<<384, 256, 0, stream>>>(z_t, VT, out_pre);
    k_out  <<<192, 256, 0, stream>>>(out_pre, Wpb, bp, (float*)d_out);
}